// Round 7
// baseline (3351.863 us; speedup 1.0000x reference)
//
#include <hip/hip_runtime.h>

typedef short bf16x8 __attribute__((ext_vector_type(8)));
typedef float f32x4 __attribute__((ext_vector_type(4)));

static constexpr int kT = 512;
static constexpr int kN = 64;
static constexpr int kD = 1024;
static constexpr int kH = 1024;
static constexpr int kG = 4 * kH;  // 4096 gate columns

__device__ __forceinline__ unsigned short f2bf(float f) {
  unsigned u = __builtin_bit_cast(unsigned, f);
  return (unsigned short)((u + 0x7fffu + ((u >> 16) & 1u)) >> 16);  // RNE
}
__device__ __forceinline__ unsigned pack2(float a, float b) {
  return (unsigned)f2bf(a) | ((unsigned)f2bf(b) << 16);
}
__device__ __forceinline__ float fsigmoid(float v) {
  return __builtin_amdgcn_rcpf(1.0f + __expf(-v));
}
__device__ __forceinline__ float ftanh(float v) {
  return 1.0f - 2.0f * __builtin_amdgcn_rcpf(__expf(2.0f * v) + 1.0f);
}

// coherent 16B load (bypass L1+L2 -> device coherence point) -- proven R4/R5
__device__ __forceinline__ bf16x8 gld16_coh(unsigned long long a) {
  bf16x8 r;
  asm volatile("global_load_dwordx4 %0, %1, off sc0 sc1" : "=v"(r) : "v"(a) : "memory");
  return r;
}
// plain cached 16B load (issue-only; readiness via later explicit vmcnt)
__device__ __forceinline__ bf16x8 gld16(unsigned long long a) {
  bf16x8 r;
  asm volatile("global_load_dwordx4 %0, %1, off" : "=v"(r) : "v"(a) : "memory");
  return r;
}

// ======================= pre-pass kernels (R6, simple, audited) =======================
__global__ __launch_bounds__(256) void xconv(const float* __restrict__ x,
                                             unsigned short* __restrict__ xbf) {
  const int gid = blockIdx.x * 256 + threadIdx.x;
  const float4* x4 = (const float4*)x;
  uint4* o = (uint4*)xbf;
  for (int i = gid; i < (kN * kT * kD) / 8; i += 2048 * 256) {
    const float4 f0 = x4[2 * i];
    const float4 f1 = x4[2 * i + 1];
    uint4 p;
    p.x = pack2(f0.x, f0.y); p.y = pack2(f0.z, f0.w);
    p.z = pack2(f1.x, f1.y); p.w = pack2(f1.z, f1.w);
    o[i] = p;
  }
}

__global__ __launch_bounds__(256) void h0conv(const float* __restrict__ h0,
                                              unsigned short* __restrict__ hbuf) {
  const int gid = blockIdx.x * 256 + threadIdx.x;  // grid 32
  const float4 f0 = ((const float4*)h0)[2 * gid];
  const float4 f1 = ((const float4*)h0)[2 * gid + 1];
  uint4 p;
  p.x = pack2(f0.x, f0.y); p.y = pack2(f0.z, f0.w);
  p.z = pack2(f1.x, f1.y); p.w = pack2(f1.z, f1.w);
  ((uint4*)hbuf)[gid] = p;
}

// Wx [1024][4096] f32 -> Wxt [4096][1024] bf16 (64x64 LDS tile transpose)
__global__ __launch_bounds__(256) void wconv(const float* __restrict__ Wx,
                                             unsigned short* __restrict__ wxt) {
  __shared__ float T[64][65];
  const int k0 = (blockIdx.x >> 6) * 64;
  const int c0 = (blockIdx.x & 63) * 64;
  const int r = threadIdx.x >> 6;
  const int cc = threadIdx.x & 63;
#pragma unroll
  for (int i = 0; i < 16; ++i)
    T[r + i * 4][cc] = Wx[(size_t)(k0 + r + i * 4) * kG + c0 + cc];
  __syncthreads();
#pragma unroll
  for (int i = 0; i < 16; ++i) {
    const int orow = r + i * 4;
    wxt[(size_t)(c0 + orow) * kD + k0 + cc] = f2bf(T[cc][orow]);
  }
}

// ========== xW GEMM: 128^2 tile, BK=64, REGISTER-staged LDS (R2-proven pattern) ==========
// A = xbf [32768][1024] bf16, Bt = wxt [4096][1024] bf16 (K-major), C = xW [32768][4096]
template <bool XF32>
__global__ __launch_bounds__(256, 2)
void xw_gemm(const unsigned short* __restrict__ A, const unsigned short* __restrict__ Bt,
             void* __restrict__ Cout) {
  __shared__ unsigned short As[128 * 64];
  __shared__ unsigned short Bs[128 * 64];
  const int tid = threadIdx.x;
  const int lane = tid & 63, wv = tid >> 6;
  const int m0 = (blockIdx.x >> 5) * 128;
  const int n0 = (blockIdx.x & 31) * 128;
  const int wm = wv >> 1, wn = wv & 1;

  f32x4 acc[4][4];
#pragma unroll
  for (int mi = 0; mi < 4; ++mi)
#pragma unroll
    for (int ni = 0; ni < 4; ++ni) acc[mi][ni] = (f32x4){0.f, 0.f, 0.f, 0.f};

  for (int kk = 0; kk < kD; kk += 64) {
    // stage: chunk c = q*256 + tid; row = c>>3; src col-bytes swizzled, LDS linear.
    uint4 av[4], bv[4];
#pragma unroll
    for (int q = 0; q < 4; ++q) {
      const int c = q * 256 + tid;
      const int row = c >> 3;
      const int so = ((c & 7) * 16) ^ ((row & 7) << 4);  // pre-swizzled source offset
      av[q] = *(const uint4*)((const char*)A + (size_t)(m0 + row) * 2048 + kk * 2 + so);
      bv[q] = *(const uint4*)((const char*)Bt + (size_t)(n0 + row) * 2048 + kk * 2 + so);
    }
    __syncthreads();  // all waves done READING As/Bs of previous step
#pragma unroll
    for (int q = 0; q < 4; ++q) {
      const int c = q * 256 + tid;  // lane-contiguous 16B writes: conflict-free
      *(uint4*)((char*)As + c * 16) = av[q];
      *(uint4*)((char*)Bs + c * 16) = bv[q];
    }
    __syncthreads();
#pragma unroll
    for (int s = 0; s < 2; ++s) {
      bf16x8 af[4], bfr[4];
#pragma unroll
      for (int i = 0; i < 4; ++i) {
        const int ar = wm * 64 + i * 16 + (lane & 15);
        af[i] = *(const bf16x8*)((const char*)As + ar * 128 +
                                 ((s * 64 + (lane >> 4) * 16) ^ ((ar & 7) << 4)));
        const int bc = wn * 64 + i * 16 + (lane & 15);
        bfr[i] = *(const bf16x8*)((const char*)Bs + bc * 128 +
                                  ((s * 64 + (lane >> 4) * 16) ^ ((bc & 7) << 4)));
      }
#pragma unroll
      for (int mi = 0; mi < 4; ++mi)
#pragma unroll
        for (int ni = 0; ni < 4; ++ni)
          acc[mi][ni] = __builtin_amdgcn_mfma_f32_16x16x32_bf16(af[mi], bfr[ni], acc[mi][ni], 0, 0, 0);
    }
  }
#pragma unroll
  for (int mi = 0; mi < 4; ++mi)
#pragma unroll
    for (int ni = 0; ni < 4; ++ni) {
      const int col = n0 + wn * 64 + ni * 16 + (lane & 15);
#pragma unroll
      for (int r = 0; r < 4; ++r) {
        const size_t row = (size_t)(m0 + wm * 64 + mi * 16 + (lane >> 4) * 4 + r);
        if (XF32)
          __builtin_nontemporal_store(acc[mi][ni][r], (float*)Cout + row * kG + col);
        else
          __builtin_nontemporal_store(f2bf(acc[mi][ni][r]),
                                      (unsigned short*)Cout + row * kG + col);
      }
    }
}

// ========== recurrence: 8 domains x 32 WGs, DEVICE-scope (all primitives R3-R5-proven) ==========
// WG bx: dom = bx&7 owns batch rows dom*8..+7; j = bx>>3 owns hidden cols j*32..+31.
// Wh resident in VGPRs (256). Barrier: per-WG owned flag line (store-only, no RMW);
// wave 0 polls the domain's 32 flags with one 32-lane load; __syncthreads releases.
template <bool XF32>
__global__ __launch_bounds__(256, 1)
void lstm_rec(const float* __restrict__ Wh, const float* __restrict__ bias,
              const void* __restrict__ xW, float* __restrict__ out,
              unsigned short* __restrict__ hbuf, unsigned int* __restrict__ cnt) {
  __shared__ float ps[32 * 320];  // 32 partial tiles, col pitch 20 (R5-proven layout)

  const int tid = threadIdx.x;
  const int bx = blockIdx.x;
  const int dom = bx & 7;
  const int j = bx >> 3;
  const int wv = tid >> 6;
  const int lane = tid & 63;

  // ---- Wh fragments resident for the whole run (B-layout proven R2..R5)
  const int kb = wv * 256;
  const int krow = (lane >> 4) * 8;
  const int lcol = lane & 15;
  bf16x8 whf[8][8];
#pragma unroll
  for (int ct = 0; ct < 8; ++ct) {
    const int gcol = (ct >> 1) * kH + j * 32 + (ct & 1) * 16 + lcol;
#pragma unroll
    for (int ks = 0; ks < 8; ++ks) {
      bf16x8 v;
#pragma unroll
      for (int e = 0; e < 8; ++e)
        v[e] = (short)f2bf(Wh[(size_t)(kb + ks * 32 + krow + e) * kG + gcol]);
      whf[ct][ks] = v;
    }
  }

  // gate identity: thread owns (n_l, jj)
  const int n_l = tid >> 5;   // 0..7
  const int jj = tid & 31;    // 0..31
  const int hcol = j * 32 + jj;
  const float b0 = bias[hcol];
  const float b1 = bias[kH + hcol];
  const float b2 = bias[2 * kH + hcol];
  const float b3 = bias[3 * kH + hcol];
  float c = 0.0f;

  // A-frag identity: rows 8..15 duplicate 0..7 (C rows >=8 unused)
  const int nrow = dom * 8 + (lane & 7);
  const unsigned long long hrow0 =
      (unsigned long long)hbuf + ((unsigned long long)nrow * kH + kb + krow) * 2;

  unsigned int* myflag = cnt + (size_t)bx * 32;                    // owned line
  unsigned int* polladdr = cnt + (size_t)(((lane & 31) * 8 + dom)) * 32;

  const unsigned* xw32 = (const unsigned*)xW;
  const unsigned short* xw16 = (const unsigned short*)xW;
  const size_t xrow0 = (size_t)(dom * 8 + n_l) * kT;

  // ---- prologue: xW(0) plain loads (compiler-fenced), then h(0) coherent loads
  unsigned xr0, xr1, xr2, xr3;
  {
    const size_t e0 = xrow0 * (size_t)kG + (size_t)hcol;
    if (XF32) {
      xr0 = xw32[e0];          xr1 = xw32[e0 + kH];
      xr2 = xw32[e0 + 2 * kH]; xr3 = xw32[e0 + 3 * kH];
    } else {
      xr0 = xw16[e0];          xr1 = xw16[e0 + kH];
      xr2 = xw16[e0 + 2 * kH]; xr3 = xw16[e0 + 3 * kH];
    }
  }
  bf16x8 hfrag[8];
#pragma unroll
  for (int ks = 0; ks < 8; ++ks) hfrag[ks] = gld16_coh(hrow0 + (unsigned)(ks * 64));

  for (int t = 0; t < kT; ++t) {
    // ---- h-half MFMAs with counted waits on the 8 in-flight h loads (rule #18)
    f32x4 acc[8];
#pragma unroll
    for (int ct = 0; ct < 8; ++ct) acc[ct] = (f32x4){0.f, 0.f, 0.f, 0.f};

    asm volatile("s_waitcnt vmcnt(4)" ::: "memory");
    __builtin_amdgcn_sched_barrier(0);
#pragma unroll
    for (int ks = 0; ks < 4; ++ks)
#pragma unroll
      for (int ct = 0; ct < 8; ++ct)
        acc[ct] = __builtin_amdgcn_mfma_f32_16x16x32_bf16(hfrag[ks], whf[ct][ks], acc[ct], 0, 0, 0);
    asm volatile("s_waitcnt vmcnt(0)" ::: "memory");
    __builtin_amdgcn_sched_barrier(0);
#pragma unroll
    for (int ks = 4; ks < 8; ++ks)
#pragma unroll
      for (int ct = 0; ct < 8; ++ct)
        acc[ct] = __builtin_amdgcn_mfma_f32_16x16x32_bf16(hfrag[ks], whf[ct][ks], acc[ct], 0, 0, 0);

    // ---- cross-wave K reduction (one ds_write_b128 per tile per lane)
#pragma unroll
    for (int ct = 0; ct < 8; ++ct)
      *(f32x4*)&ps[(ct * 4 + wv) * 320 + (lane & 15) * 20 + (lane >> 4) * 4] = acc[ct];
    __syncthreads();

    float a4[4];
#pragma unroll
    for (int g = 0; g < 4; ++g) {
      const int ctb = (g * 2 + (jj >> 4)) * 4;
      const int cw = (jj & 15) * 20 + n_l;
      a4[g] = ps[(ctb + 0) * 320 + cw] + ps[(ctb + 1) * 320 + cw]
            + ps[(ctb + 2) * 320 + cw] + ps[(ctb + 3) * 320 + cw];
    }
    const float xv0 = __builtin_bit_cast(float, XF32 ? xr0 : (xr0 << 16));
    const float xv1 = __builtin_bit_cast(float, XF32 ? xr1 : (xr1 << 16));
    const float xv2 = __builtin_bit_cast(float, XF32 ? xr2 : (xr2 << 16));
    const float xv3 = __builtin_bit_cast(float, XF32 ? xr3 : (xr3 << 16));
    const float gi = fsigmoid(a4[0] + xv0 + b0);
    const float gf = fsigmoid(a4[1] + xv1 + b1);
    const float go = fsigmoid(a4[2] + xv2 + b2);
    const float gg = ftanh(a4[3] + xv3 + b3);
    c = gf * c + gi * gg;
    const float hv = go * ftanh(c);

    if (t < kT - 1) {
      const int buf1 = (t + 1) & 1;
      // ---- publish h(t+1): paired dword agent-scope store (R3-R5-proven)
      const unsigned mybf = (unsigned)f2bf(hv);
      const unsigned up = (unsigned)__shfl_xor((int)mybf, 1);
      if ((jj & 1) == 0) {
        const size_t eidx = (size_t)buf1 * (kN * kH) +
                            (size_t)(dom * 8 + n_l) * kH + (size_t)hcol;
        __hip_atomic_store((unsigned*)(hbuf + eidx), mybf | (up << 16),
                           __ATOMIC_RELAXED, __HIP_MEMORY_SCOPE_AGENT);
      }
      asm volatile("s_waitcnt vmcnt(0)" ::: "memory");  // explicit per-wave drain
      __syncthreads();  // all waves' publishes at coherence point

      if (tid == 0)
        __hip_atomic_store(myflag, (unsigned)(t + 1),
                           __ATOMIC_RELAXED, __HIP_MEMORY_SCOPE_AGENT);

      // out store + xW(t+1) prefetch: off the critical path (drained at release
      // barrier for non-pollers, at the poll's value-wait for wave 0)
      __builtin_nontemporal_store(hv, &out[(xrow0 + t) * kH + hcol]);
      {
        const size_t e1 = (xrow0 + t + 1) * (size_t)kG + (size_t)hcol;
        if (XF32) {
          xr0 = xw32[e1];          xr1 = xw32[e1 + kH];
          xr2 = xw32[e1 + 2 * kH]; xr3 = xw32[e1 + 3 * kH];
        } else {
          xr0 = xw16[e1];          xr1 = xw16[e1 + kH];
          xr2 = xw16[e1 + 2 * kH]; xr3 = xw16[e1 + 3 * kH];
        }
      }

      // ---- wave 0 polls the domain's 32 flags; barrier releases the WG
      if (wv == 0) {
        const int tgt = t + 1;
        for (;;) {
          unsigned v = __hip_atomic_load(polladdr, __ATOMIC_RELAXED,
                                         __HIP_MEMORY_SCOPE_AGENT);
          if (__all((int)v >= tgt)) break;
          __builtin_amdgcn_s_sleep(2);
        }
      }
      __syncthreads();
      __builtin_amdgcn_sched_barrier(0);

      // ---- issue h(t+1): exactly 8 outstanding per wave at next loop top
      const unsigned long long hb = hrow0 + (unsigned long long)buf1 * (kN * kH * 2);
#pragma unroll
      for (int ks = 0; ks < 8; ++ks) hfrag[ks] = gld16_coh(hb + (unsigned)(ks * 64));
    } else {
      __builtin_nontemporal_store(hv, &out[(xrow0 + t) * kH + hcol]);
    }
  }
}

// ======================= tier B/C: round-5 kernel (proven fallback) =======================
template <bool PRE>
__global__ __launch_bounds__(256, 1)
void lstm_persistent(const float* __restrict__ x, const float* __restrict__ h0,
                     const float* __restrict__ Wx, const float* __restrict__ Wh,
                     const float* __restrict__ bias, float* __restrict__ out,
                     unsigned short* __restrict__ hbuf, unsigned int* __restrict__ cnt,
                     const unsigned short* __restrict__ xbf) {
  __shared__ float ps[16 * 320];

  const int tid = threadIdx.x;
  const int bx = blockIdx.x;
  const int dom = (bx & 7) >> 1;
  const int ug = ((bx >> 3) << 1) | (bx & 1);
  const int wv = tid >> 6;
  const int lane = tid & 63;

  const int colc = ug * 16 + (lane & 15);
  const int krow = (lane >> 4) * 8;
  const int kb = wv * 256;
  bf16x8 wxf[4][8], whf[4][8];
#pragma unroll
  for (int ct = 0; ct < 4; ++ct) {
#pragma unroll
    for (int ks = 0; ks < 8; ++ks) {
      bf16x8 vx, vh;
#pragma unroll
      for (int e = 0; e < 8; ++e) {
        const size_t k = (size_t)(kb + ks * 32 + krow + e);
        vx[e] = (short)f2bf(Wx[k * kG + ct * kH + colc]);
        vh[e] = (short)f2bf(Wh[k * kG + ct * kH + colc]);
      }
      wxf[ct][ks] = vx;
      whf[ct][ks] = vh;
    }
  }

  const int n_l = tid >> 4;
  const int j_l = tid & 15;
  const int jg = ug * 16 + j_l;
  const float b_i = bias[jg];
  const float b_f = bias[kH + jg];
  const float b_o = bias[2 * kH + jg];
  const float b_g = bias[3 * kH + jg];
  float c = 0.0f;

  const int arow = lane & 15;
  const int nrow = dom * 16 + arow;
  const unsigned long long xbase0 =
      (unsigned long long)nrow * kT * kD * 2 + (unsigned long long)(kb + krow) * 2;
  const unsigned long long hbase0 =
      (unsigned long long)nrow * kH * 2 + (unsigned long long)(kb + krow) * 2;

  unsigned int* mycnt = cnt + (size_t)(dom * 64 + ug) * 32;
  unsigned int* dflag = cnt + 8192 + (size_t)dom * 32;
  const bool is_agg = (ug == 0) && (wv == 0);

  bf16x8 xfrag[8], hfrag[8];

  if (PRE) {
    const unsigned long long xb = (unsigned long long)xbf + xbase0;
#pragma unroll
    for (int ks = 0; ks < 8; ++ks) xfrag[ks] = gld16(xb + (unsigned)(ks * 64));
  } else {
    const float* xr = x + (size_t)nrow * kT * kD + (kb + krow);
#pragma unroll
    for (int ks = 0; ks < 8; ++ks) {
      const float4 f0 = *(const float4*)(xr + ks * 32);
      const float4 f1 = *(const float4*)(xr + ks * 32 + 4);
      bf16x8 v;
      v[0] = (short)f2bf(f0.x); v[1] = (short)f2bf(f0.y);
      v[2] = (short)f2bf(f0.z); v[3] = (short)f2bf(f0.w);
      v[4] = (short)f2bf(f1.x); v[5] = (short)f2bf(f1.y);
      v[6] = (short)f2bf(f1.z); v[7] = (short)f2bf(f1.w);
      xfrag[ks] = v;
    }
  }
  {
    const float* hr = h0 + (size_t)nrow * kH + (kb + krow);
#pragma unroll
    for (int ks = 0; ks < 8; ++ks) {
      const float4 f0 = *(const float4*)(hr + ks * 32);
      const float4 f1 = *(const float4*)(hr + ks * 32 + 4);
      bf16x8 v;
      v[0] = (short)f2bf(f0.x); v[1] = (short)f2bf(f0.y);
      v[2] = (short)f2bf(f0.z); v[3] = (short)f2bf(f0.w);
      v[4] = (short)f2bf(f1.x); v[5] = (short)f2bf(f1.y);
      v[6] = (short)f2bf(f1.z); v[7] = (short)f2bf(f1.w);
      hfrag[ks] = v;
    }
  }
  asm volatile("s_waitcnt vmcnt(0)" ::: "memory");
  __builtin_amdgcn_sched_barrier(0);

  f32x4 acc[4];
#pragma unroll
  for (int ct = 0; ct < 4; ++ct) acc[ct] = (f32x4){0.f, 0.f, 0.f, 0.f};
#pragma unroll
  for (int ks = 0; ks < 8; ++ks)
#pragma unroll
    for (int ct = 0; ct < 4; ++ct)
      acc[ct] = __builtin_amdgcn_mfma_f32_16x16x32_bf16(xfrag[ks], wxf[ct][ks], acc[ct], 0, 0, 0);

  for (int t = 0; t < kT; ++t) {
    asm volatile("s_waitcnt vmcnt(4)" ::: "memory");
    __builtin_amdgcn_sched_barrier(0);
#pragma unroll
    for (int ks = 0; ks < 4; ++ks)
#pragma unroll
      for (int ct = 0; ct < 4; ++ct)
        acc[ct] = __builtin_amdgcn_mfma_f32_16x16x32_bf16(hfrag[ks], whf[ct][ks], acc[ct], 0, 0, 0);
    asm volatile("s_waitcnt vmcnt(0)" ::: "memory");
    __builtin_amdgcn_sched_barrier(0);
#pragma unroll
    for (int ks = 4; ks < 8; ++ks)
#pragma unroll
      for (int ct = 0; ct < 4; ++ct)
        acc[ct] = __builtin_amdgcn_mfma_f32_16x16x32_bf16(hfrag[ks], whf[ct][ks], acc[ct], 0, 0, 0);

#pragma unroll
    for (int ct = 0; ct < 4; ++ct) {
      const int o = (ct * 4 + wv) * 320 + (lane & 15) * 20 + (lane >> 4) * 4;
      *(f32x4*)&ps[o] = acc[ct];
    }
    __syncthreads();

    float a4[4];
#pragma unroll
    for (int g = 0; g < 4; ++g) {
      a4[g] = ps[(g * 4 + 0) * 320 + j_l * 20 + n_l]
            + ps[(g * 4 + 1) * 320 + j_l * 20 + n_l]
            + ps[(g * 4 + 2) * 320 + j_l * 20 + n_l]
            + ps[(g * 4 + 3) * 320 + j_l * 20 + n_l];
    }
    const float gi = fsigmoid(a4[0] + b_i);
    const float gf = fsigmoid(a4[1] + b_f);
    const float go = fsigmoid(a4[2] + b_o);
    const float gg = ftanh(a4[3] + b_g);
    c = gf * c + gi * gg;
    const float hv = go * ftanh(c);

    if (t < kT - 1) {
      const unsigned mybf = (unsigned)f2bf(hv);
      const unsigned up = (unsigned)__shfl_xor((int)mybf, 1);
      if ((j_l & 1) == 0) {
        const size_t eidx = (size_t)((t + 1) & 1) * (kN * kH) +
                            (size_t)(dom * 16 + n_l) * kH + (size_t)(ug * 16 + j_l);
        __hip_atomic_store((unsigned*)(hbuf + eidx), mybf | (up << 16),
                           __ATOMIC_RELAXED, __HIP_MEMORY_SCOPE_AGENT);
      }
      asm volatile("s_waitcnt vmcnt(0)" ::: "memory");
      __builtin_amdgcn_sched_barrier(0);
      if (lane == 0)
        __hip_atomic_fetch_add(mycnt, 1u, __ATOMIC_RELAXED, __HIP_MEMORY_SCOPE_AGENT);

      __builtin_nontemporal_store(hv, &out[((size_t)(dom * 16 + n_l) * kT + t) * kH + jg]);

      if (PRE) {
        const unsigned long long xb = (unsigned long long)xbf + xbase0 +
                                      (unsigned long long)(t + 1) * 2048u;
#pragma unroll
        for (int ks = 0; ks < 8; ++ks) xfrag[ks] = gld16(xb + (unsigned)(ks * 64));
        asm volatile("s_waitcnt vmcnt(0)" ::: "memory");
        __builtin_amdgcn_sched_barrier(0);
      } else {
        const float* xr = x + (size_t)nrow * kT * kD + (size_t)(t + 1) * kD + (kb + krow);
#pragma unroll
        for (int ks = 0; ks < 8; ++ks) {
          const float4 f0 = *(const float4*)(xr + ks * 32);
          const float4 f1 = *(const float4*)(xr + ks * 32 + 4);
          bf16x8 v;
          v[0] = (short)f2bf(f0.x); v[1] = (short)f2bf(f0.y);
          v[2] = (short)f2bf(f0.z); v[3] = (short)f2bf(f0.w);
          v[4] = (short)f2bf(f1.x); v[5] = (short)f2bf(f1.y);
          v[6] = (short)f2bf(f1.z); v[7] = (short)f2bf(f1.w);
          xfrag[ks] = v;
        }
      }
#pragma unroll
      for (int ct = 0; ct < 4; ++ct) acc[ct] = (f32x4){0.f, 0.f, 0.f, 0.f};
#pragma unroll
      for (int ks = 0; ks < 8; ++ks)
#pragma unroll
        for (int ct = 0; ct < 4; ++ct)
          acc[ct] = __builtin_amdgcn_mfma_f32_16x16x32_bf16(xfrag[ks], wxf[ct][ks], acc[ct], 0, 0, 0);

      const unsigned tgt = (unsigned)(t + 1);
      if (is_agg) {
        for (;;) {
          unsigned v = __hip_atomic_load(cnt + (size_t)(dom * 64 + lane) * 32,
                                         __ATOMIC_RELAXED, __HIP_MEMORY_SCOPE_AGENT);
#pragma unroll
          for (int s = 1; s < 64; s <<= 1) v += (unsigned)__shfl_xor((int)v, s);
          if (v >= 256u * tgt) break;
          __builtin_amdgcn_s_sleep(1);
        }
        if (lane == 0)
          __hip_atomic_store(dflag, tgt, __ATOMIC_RELAXED, __HIP_MEMORY_SCOPE_AGENT);
      } else if (lane == 0) {
        while (__hip_atomic_load(dflag, __ATOMIC_RELAXED, __HIP_MEMORY_SCOPE_AGENT) < tgt)
          __builtin_amdgcn_s_sleep(1);
      }
      asm volatile("" ::: "memory");
      __builtin_amdgcn_sched_barrier(0);

      const unsigned long long hb = (unsigned long long)hbuf +
                                    (unsigned long long)((t + 1) & 1) * (kN * kH * 2) +
                                    hbase0;
#pragma unroll
      for (int ks = 0; ks < 8; ++ks) hfrag[ks] = gld16_coh(hb + (unsigned)(ks * 64));
    } else {
      __builtin_nontemporal_store(hv, &out[((size_t)(dom * 16 + n_l) * kT + t) * kH + jg]);
    }
  }
}

// ======================= launch =======================
extern "C" void kernel_launch(void* const* d_in, const int* in_sizes, int n_in,
                              void* d_out, int out_size, void* d_ws, size_t ws_size,
                              hipStream_t stream) {
  (void)in_sizes; (void)n_in; (void)out_size;
  const float* x  = (const float*)d_in[0];
  const float* h0 = (const float*)d_in[1];
  const float* Wx = (const float*)d_in[2];
  const float* Wh = (const float*)d_in[3];
  const float* b  = (const float*)d_in[4];
  float* out = (float*)d_out;

  const size_t CNT = 36864;
  const size_t o_hbuf = CNT;                         // 256 KB
  const size_t o_xbf = o_hbuf + 262144;              // 64 MB
  const size_t o_wxt = o_xbf + 67108864;             // 8 MB
  const size_t o_xw = o_wxt + 8388608;
  const size_t need_f32 = o_xw + (size_t)536870912;  // xW f32
  const size_t need_b16 = o_xw + (size_t)268435456;  // xW bf16

  unsigned int* cnt = (unsigned int*)d_ws;
  unsigned short* hbuf = (unsigned short*)((char*)d_ws + o_hbuf);
  unsigned short* xbf = (unsigned short*)((char*)d_ws + o_xbf);
  unsigned short* wxt = (unsigned short*)((char*)d_ws + o_wxt);
  void* xw = (void*)((char*)d_ws + o_xw);

  hipMemsetAsync(d_ws, 0, CNT, stream);  // reset flags (graph-capture legal)

  if (ws_size >= need_b16) {
    const bool f32p = (ws_size >= need_f32);
    hipLaunchKernelGGL(h0conv, dim3(32), dim3(256), 0, stream, h0, hbuf);
    hipLaunchKernelGGL(xconv, dim3(2048), dim3(256), 0, stream, x, xbf);
    hipLaunchKernelGGL(wconv, dim3(1024), dim3(256), 0, stream, Wx, wxt);
    if (f32p) {
      hipLaunchKernelGGL(HIP_KERNEL_NAME(xw_gemm<true>), dim3(8192), dim3(256), 0, stream,
                         xbf, wxt, xw);
      hipLaunchKernelGGL(HIP_KERNEL_NAME(lstm_rec<true>), dim3(256), dim3(256), 0, stream,
                         Wh, b, xw, out, hbuf, cnt);
    } else {
      hipLaunchKernelGGL(HIP_KERNEL_NAME(xw_gemm<false>), dim3(8192), dim3(256), 0, stream,
                         xbf, wxt, xw);
      hipLaunchKernelGGL(HIP_KERNEL_NAME(lstm_rec<false>), dim3(256), dim3(256), 0, stream,
                         Wh, b, xw, out, hbuf, cnt);
    }
  } else if (ws_size >= o_wxt) {  // room for xbf: proven round-5 path
    hipLaunchKernelGGL(xconv, dim3(2048), dim3(256), 0, stream, x, xbf);
    hipLaunchKernelGGL(HIP_KERNEL_NAME(lstm_persistent<true>), dim3(256), dim3(256),
                       0, stream, x, h0, Wx, Wh, b, out, hbuf, cnt, xbf);
  } else {
    hipLaunchKernelGGL(HIP_KERNEL_NAME(lstm_persistent<false>), dim3(256), dim3(256),
                       0, stream, x, h0, Wx, Wh, b, out, hbuf, cnt,
                       (const unsigned short*)nullptr);
  }
}

// Round 10
// 2010.798 us; speedup vs baseline: 1.6669x; 1.6669x over previous
//
#include <hip/hip_runtime.h>

typedef short bf16x8 __attribute__((ext_vector_type(8)));
typedef float f32x4 __attribute__((ext_vector_type(4)));

static constexpr int kT = 512;
static constexpr int kN = 64;
static constexpr int kD = 1024;
static constexpr int kH = 1024;
static constexpr int kG = 4 * kH;  // 4096 gate columns

__device__ __forceinline__ unsigned short f2bf(float f) {
  unsigned u = __builtin_bit_cast(unsigned, f);
  return (unsigned short)((u + 0x7fffu + ((u >> 16) & 1u)) >> 16);  // RNE
}
__device__ __forceinline__ unsigned pack2(float a, float b) {
  return (unsigned)f2bf(a) | ((unsigned)f2bf(b) << 16);
}
__device__ __forceinline__ float fsigmoid(float v) {
  return __builtin_amdgcn_rcpf(1.0f + __expf(-v));
}
__device__ __forceinline__ float ftanh(float v) {
  return 1.0f - 2.0f * __builtin_amdgcn_rcpf(__expf(2.0f * v) + 1.0f);
}

// one-shot coherent 16B load, used ONLY after a proven flag barrier (R4/R5/R7
// pattern). NEVER spin on raw-asm loads (R6/R8/R9 all livelocked doing that).
__device__ __forceinline__ bf16x8 gld16_coh(unsigned long long a) {
  bf16x8 r;
  asm volatile("global_load_dwordx4 %0, %1, off sc0 sc1" : "=v"(r) : "v"(a) : "memory");
  return r;
}
// plain cached 16B load (issue-only; readiness via later explicit vmcnt)
__device__ __forceinline__ bf16x8 gld16(unsigned long long a) {
  bf16x8 r;
  asm volatile("global_load_dwordx4 %0, %1, off" : "=v"(r) : "v"(a) : "memory");
  return r;
}

// pre-pass: x fp32 -> bf16 (R2..R7-proven)
__global__ __launch_bounds__(256) void xconv(const float* __restrict__ x,
                                             unsigned short* __restrict__ xbf) {
  const int gid = blockIdx.x * 256 + threadIdx.x;
  const float4* x4 = (const float4*)x;
  uint4* o = (uint4*)xbf;
  for (int i = gid; i < (kN * kT * kD) / 8; i += 2048 * 256) {
    const float4 f0 = x4[2 * i];
    const float4 f1 = x4[2 * i + 1];
    uint4 p;
    p.x = pack2(f0.x, f0.y); p.y = pack2(f0.z, f0.w);
    p.z = pack2(f1.x, f1.y); p.w = pack2(f1.z, f1.w);
    o[i] = p;
  }
}

// ============== fine-grained-flag LSTM (R5 machinery, per-wave dependencies) ==============
// 256 WGs x 256 threads, 1 WG/CU. WG (dom, ug): batch rows dom*16..+15, hidden
// cols ug*16..+15; Wx+Wh resident in VGPRs, K-split over 4 waves (R5-proven).
// Barrier graph: producer wave wv of WG ug publishes rows wv*4..+3 (paired-dword
// agent atomics), drains its own stores (vmcnt(0)), lane0 flag-stores
// flags[dom*256+ug*4+wv]=t+1. Consumer wave wv depends ONLY on WGs
// ug' in [wv*16, wv*16+16): lane l polls flags[dom*256+wv*64+l] via
// __hip_atomic_load (the ONLY proven spin primitive), then one-shot coherent
// h-frag loads. ABA-free: each WG's 4-wave poll union covers all 64 domain WGs,
// so no producer can lap a buffer. flags memset in-graph each launch.
template <bool PRE>
__global__ __launch_bounds__(256, 1)
void lstm_fg(const float* __restrict__ x, const float* __restrict__ h0,
             const float* __restrict__ Wx, const float* __restrict__ Wh,
             const float* __restrict__ bias, float* __restrict__ out,
             unsigned short* __restrict__ hbuf, unsigned* __restrict__ flags,
             const unsigned short* __restrict__ xbf) {
  __shared__ float ps[2][16 * 320];  // double-buffered partials -> 1 sync/step

  const int tid = threadIdx.x;
  const int bx = blockIdx.x;
  const int dom = (bx & 7) >> 1;                 // 0..3
  const int ug = ((bx >> 3) << 1) | (bx & 1);    // 0..63
  const int wv = tid >> 6;                       // wave 0..3 (K-split)
  const int lane = tid & 63;

  // ---- weight fragments resident in VGPRs (R5-proven layout)
  const int colc = ug * 16 + (lane & 15);
  const int krow = (lane >> 4) * 8;
  const int kb = wv * 256;
  bf16x8 wxf[4][8], whf[4][8];
#pragma unroll
  for (int ct = 0; ct < 4; ++ct) {
#pragma unroll
    for (int ks = 0; ks < 8; ++ks) {
      bf16x8 vx, vh;
#pragma unroll
      for (int e = 0; e < 8; ++e) {
        const size_t k = (size_t)(kb + ks * 32 + krow + e);
        vx[e] = (short)f2bf(Wx[k * kG + ct * kH + colc]);
        vh[e] = (short)f2bf(Wh[k * kG + ct * kH + colc]);
      }
      wxf[ct][ks] = vx;
      whf[ct][ks] = vh;
    }
  }

  // gate identity
  const int n_l = tid >> 4;
  const int j_l = tid & 15;
  const int jg = ug * 16 + j_l;
  const float b_i = bias[jg];
  const float b_f = bias[kH + jg];
  const float b_o = bias[2 * kH + jg];
  const float b_g = bias[3 * kH + jg];
  float c = 0.0f;

  // A-frag / publish identity
  const int arow = lane & 15;
  const int nrow = dom * 16 + arow;
  const unsigned long long xbase0 =
      (unsigned long long)nrow * kT * kD * 2 + (unsigned long long)(kb + krow) * 2;
  const unsigned long long hbase0 =
      (unsigned long long)nrow * kH * 2 + (unsigned long long)(kb + krow) * 2;
  const unsigned pubeidx = (unsigned)((dom * 16 + n_l) * kH + jg);  // element idx

  // flag plumbing: producer flag dword + per-lane poll address
  unsigned* myflag = flags + (dom * 256 + ug * 4 + wv);
  unsigned* pollp = flags + (dom * 256 + wv * 64 + lane);

  bf16x8 xfrag[8], hfrag[8];

  // ---- prologue: x(0) frags
  if (PRE) {
    const unsigned long long xb = (unsigned long long)xbf + xbase0;
#pragma unroll
    for (int ks = 0; ks < 8; ++ks) xfrag[ks] = gld16(xb + (unsigned)(ks * 64));
    asm volatile("s_waitcnt vmcnt(0)" ::: "memory");
    __builtin_amdgcn_sched_barrier(0);
  } else {
    const float* xr = x + (size_t)nrow * kT * kD + (kb + krow);
#pragma unroll
    for (int ks = 0; ks < 8; ++ks) {
      const float4 f0 = *(const float4*)(xr + ks * 32);
      const float4 f1 = *(const float4*)(xr + ks * 32 + 4);
      bf16x8 v;
      v[0] = (short)f2bf(f0.x); v[1] = (short)f2bf(f0.y);
      v[2] = (short)f2bf(f0.z); v[3] = (short)f2bf(f0.w);
      v[4] = (short)f2bf(f1.x); v[5] = (short)f2bf(f1.y);
      v[6] = (short)f2bf(f1.z); v[7] = (short)f2bf(f1.w);
      xfrag[ks] = v;
    }
  }
  // x-half of step 0
  f32x4 acc[4];
#pragma unroll
  for (int ct = 0; ct < 4; ++ct) acc[ct] = (f32x4){0.f, 0.f, 0.f, 0.f};
#pragma unroll
  for (int ks = 0; ks < 8; ++ks)
#pragma unroll
    for (int ct = 0; ct < 4; ++ct)
      acc[ct] = __builtin_amdgcn_mfma_f32_16x16x32_bf16(xfrag[ks], wxf[ct][ks], acc[ct], 0, 0, 0);
  // h(0) from h0 (fp32 -> bf16, compiler-managed loads/waits)
  {
    const float* hr = h0 + (size_t)nrow * kH + (kb + krow);
#pragma unroll
    for (int ks = 0; ks < 8; ++ks) {
      const float4 f0 = *(const float4*)(hr + ks * 32);
      const float4 f1 = *(const float4*)(hr + ks * 32 + 4);
      bf16x8 v;
      v[0] = (short)f2bf(f0.x); v[1] = (short)f2bf(f0.y);
      v[2] = (short)f2bf(f0.z); v[3] = (short)f2bf(f0.w);
      v[4] = (short)f2bf(f1.x); v[5] = (short)f2bf(f1.y);
      v[6] = (short)f2bf(f1.z); v[7] = (short)f2bf(f1.w);
      hfrag[ks] = v;
    }
  }

  for (int t = 0; t < kT; ++t) {
    // ---- h-half MFMAs: counted waits on the 8 in-flight h loads (0 at t=0)
    asm volatile("s_waitcnt vmcnt(4)" ::: "memory");
    __builtin_amdgcn_sched_barrier(0);
#pragma unroll
    for (int ks = 0; ks < 4; ++ks)
#pragma unroll
      for (int ct = 0; ct < 4; ++ct)
        acc[ct] = __builtin_amdgcn_mfma_f32_16x16x32_bf16(hfrag[ks], whf[ct][ks], acc[ct], 0, 0, 0);
    asm volatile("s_waitcnt vmcnt(0)" ::: "memory");
    __builtin_amdgcn_sched_barrier(0);
#pragma unroll
    for (int ks = 4; ks < 8; ++ks)
#pragma unroll
      for (int ct = 0; ct < 4; ++ct)
        acc[ct] = __builtin_amdgcn_mfma_f32_16x16x32_bf16(hfrag[ks], whf[ct][ks], acc[ct], 0, 0, 0);

    // ---- cross-wave K reduction (double-buffered ps -> single sync per step)
    float* p = ps[t & 1];
#pragma unroll
    for (int ct = 0; ct < 4; ++ct)
      *(f32x4*)&p[(ct * 4 + wv) * 320 + (lane & 15) * 20 + (lane >> 4) * 4] = acc[ct];
    __syncthreads();

    float a4[4];
#pragma unroll
    for (int g = 0; g < 4; ++g) {
      a4[g] = p[(g * 4 + 0) * 320 + j_l * 20 + n_l]
            + p[(g * 4 + 1) * 320 + j_l * 20 + n_l]
            + p[(g * 4 + 2) * 320 + j_l * 20 + n_l]
            + p[(g * 4 + 3) * 320 + j_l * 20 + n_l];
    }
    const float gi = fsigmoid(a4[0] + b_i);
    const float gf = fsigmoid(a4[1] + b_f);
    const float go = fsigmoid(a4[2] + b_o);
    const float gg = ftanh(a4[3] + b_g);
    c = gf * c + gi * gg;
    const float hv = go * ftanh(c);

    if (t < kT - 1) {
      const unsigned tgt = (unsigned)(t + 1);
      const unsigned buf1 = tgt & 1;
      // ---- publish h(t+1): paired-dword agent-scope atomic store (R5-proven)
      const unsigned mybf = (unsigned)f2bf(hv);
      const unsigned up = (unsigned)__shfl_xor((int)mybf, 1);
      if ((j_l & 1) == 0) {
        __hip_atomic_store((unsigned*)(hbuf + buf1 * (kN * kH) + pubeidx),
                           mybf | (up << 16), __ATOMIC_RELAXED, __HIP_MEMORY_SCOPE_AGENT);
      }
      // per-wave drain (only this wave's ~32 publish stores outstanding)
      asm volatile("s_waitcnt vmcnt(0)" ::: "memory");
      __builtin_amdgcn_sched_barrier(0);
      // this wave's rows are globally visible -> raise this wave's flag
      if (lane == 0)
        __hip_atomic_store(myflag, tgt, __ATOMIC_RELAXED, __HIP_MEMORY_SCOPE_AGENT);

      // out store: off the critical path (drained by the xfrag vmcnt below)
      __builtin_nontemporal_store(hv, &out[((size_t)(dom * 16 + n_l) * kT + t) * kH + jg]);

      // ---- x(t+1) frags + x-half MFMAs (fills the flag-transit window)
      if (PRE) {
        const unsigned long long xb = (unsigned long long)xbf + xbase0 +
                                      (unsigned long long)(t + 1) * 2048u;
#pragma unroll
        for (int ks = 0; ks < 8; ++ks) xfrag[ks] = gld16(xb + (unsigned)(ks * 64));
        asm volatile("s_waitcnt vmcnt(0)" ::: "memory");
        __builtin_amdgcn_sched_barrier(0);
      } else {
        const float* xr = x + (size_t)nrow * kT * kD + (size_t)(t + 1) * kD + (kb + krow);
#pragma unroll
        for (int ks = 0; ks < 8; ++ks) {
          const float4 f0 = *(const float4*)(xr + ks * 32);
          const float4 f1 = *(const float4*)(xr + ks * 32 + 4);
          bf16x8 v;
          v[0] = (short)f2bf(f0.x); v[1] = (short)f2bf(f0.y);
          v[2] = (short)f2bf(f0.z); v[3] = (short)f2bf(f0.w);
          v[4] = (short)f2bf(f1.x); v[5] = (short)f2bf(f1.y);
          v[6] = (short)f2bf(f1.z); v[7] = (short)f2bf(f1.w);
          xfrag[ks] = v;
        }
      }
#pragma unroll
      for (int ct = 0; ct < 4; ++ct) acc[ct] = (f32x4){0.f, 0.f, 0.f, 0.f};
#pragma unroll
      for (int ks = 0; ks < 8; ++ks)
#pragma unroll
        for (int ct = 0; ct < 4; ++ct)
          acc[ct] = __builtin_amdgcn_mfma_f32_16x16x32_bf16(xfrag[ks], wxf[ct][ks], acc[ct], 0, 0, 0);

      // ---- fine-grained poll: lane l watches producer-wave flag l (16 WGs x 4)
      for (;;) {
        const unsigned v = __hip_atomic_load(pollp, __ATOMIC_RELAXED,
                                             __HIP_MEMORY_SCOPE_AGENT);
        if (__all((int)v >= (int)tgt)) break;
        __builtin_amdgcn_s_sleep(1);
      }
      __builtin_amdgcn_sched_barrier(0);

      // ---- one-shot coherent h(t+1) loads (proven post-barrier pattern)
      const unsigned long long hb = (unsigned long long)hbuf +
                                    (unsigned long long)buf1 * (kN * kH * 2) + hbase0;
#pragma unroll
      for (int ks = 0; ks < 8; ++ks) hfrag[ks] = gld16_coh(hb + (unsigned)(ks * 64));
    } else {
      __builtin_nontemporal_store(hv, &out[((size_t)(dom * 16 + n_l) * kT + t) * kH + jg]);
    }
  }
}

// ======================= launch =======================
extern "C" void kernel_launch(void* const* d_in, const int* in_sizes, int n_in,
                              void* d_out, int out_size, void* d_ws, size_t ws_size,
                              hipStream_t stream) {
  (void)in_sizes; (void)n_in; (void)out_size;
  const float* x  = (const float*)d_in[0];
  const float* h0 = (const float*)d_in[1];
  const float* Wx = (const float*)d_in[2];
  const float* Wh = (const float*)d_in[3];
  const float* b  = (const float*)d_in[4];
  float* out = (float*)d_out;

  // ws: [0,4KB) wave flags | [4KB,+256KB) h double buffer | [260KB,+64MB) bf16 x
  const size_t o_hbuf = 4096;
  const size_t o_xbf = o_hbuf + 262144;
  const size_t need_pre = o_xbf + (size_t)kN * kT * kD * 2;

  unsigned* flags = (unsigned*)d_ws;
  unsigned short* hbuf = (unsigned short*)((char*)d_ws + o_hbuf);
  unsigned short* xbf = (unsigned short*)((char*)d_ws + o_xbf);

  hipMemsetAsync(d_ws, 0, 4096, stream);  // reset flags (in-graph, replay-safe)

  if (ws_size >= need_pre) {
    hipLaunchKernelGGL(xconv, dim3(2048), dim3(256), 0, stream, x, xbf);
    hipLaunchKernelGGL(HIP_KERNEL_NAME(lstm_fg<true>), dim3(256), dim3(256), 0, stream,
                       x, h0, Wx, Wh, b, out, hbuf, flags, xbf);
  } else {
    hipLaunchKernelGGL(HIP_KERNEL_NAME(lstm_fg<false>), dim3(256), dim3(256), 0, stream,
                       x, h0, Wx, Wh, b, out, hbuf, flags,
                       (const unsigned short*)nullptr);
  }
}